// Round 1
// baseline (341.865 us; speedup 1.0000x reference)
//
#include <hip/hip_runtime.h>
#include <hip/hip_bf16.h>
#include <cstdint>
#include <cstddef>

typedef _Float16 h2 __attribute__((ext_vector_type(2)));
typedef _Float16 h4 __attribute__((ext_vector_type(4)));
typedef _Float16 h8 __attribute__((ext_vector_type(8)));
typedef float    f4 __attribute__((ext_vector_type(4)));

#define SEQ 4096
#define EMB 1280
#define NH 16
#define HD 80
#define QKV_LD 3840

// ---------------- fp32 -> f16 convert ----------------
__global__ __launch_bounds__(256) void k_convert(const float* __restrict__ in,
                                                 _Float16* __restrict__ out, int n4) {
  int i = blockIdx.x * 256 + threadIdx.x;
  if (i < n4) {
    f4 v = ((const f4*)in)[i];
    h4 o; o[0] = (_Float16)v[0]; o[1] = (_Float16)v[1];
    o[2] = (_Float16)v[2]; o[3] = (_Float16)v[3];
    ((h4*)out)[i] = o;
  }
}

// ---------------- transpose + convert: in (R,C) fp32 -> out (C,R) f16 ----------------
__global__ __launch_bounds__(256) void k_transpose(const float* __restrict__ in,
                                                   _Float16* __restrict__ out, int R, int C) {
  __shared__ _Float16 tile[64][68];
  int ct = C >> 6;
  int rB = (blockIdx.x / ct) << 6;
  int cB = (blockIdx.x % ct) << 6;
#pragma unroll 4
  for (int i = 0; i < 16; i++) {
    int idx = i * 256 + threadIdx.x;
    int r = idx >> 6, c = idx & 63;
    tile[r][c] = (_Float16)in[(size_t)(rB + r) * C + cB + c];
  }
  __syncthreads();
#pragma unroll 4
  for (int i = 0; i < 16; i++) {
    int idx = i * 256 + threadIdx.x;
    int c = idx >> 6, r = idx & 63;
    out[(size_t)(cB + c) * R + rB + r] = tile[r][c];
  }
}

// ---------------- GEMM: C(M,N) = A(M,K) * B(N,K)^T + bias ----------------
// 256 threads = 4 waves (2x2), tile 128x128, BK=32, 16x16x32 f16 MFMA.
// Swapped operands: mfma(bf, af) -> C^T frag: lane holds rows n=g*4+r, col m=l15
// -> 4 consecutive OUTPUT COLUMNS per lane -> vector stores + vector bias load.
template <bool OUT_F32>
__global__ __launch_bounds__(256) void k_gemm(const _Float16* __restrict__ A,
                                              const _Float16* __restrict__ B,
                                              const float* __restrict__ bias,
                                              void* __restrict__ Cout,
                                              int M, int N, int K) {
  __shared__ _Float16 As[128][40];
  __shared__ _Float16 Bs[128][40];
  int tid = threadIdx.x;
  int lane = tid & 63, wave = tid >> 6;
  int wr = wave >> 1, wc = wave & 1;
  int l15 = lane & 15, g = lane >> 4;
  int nt = N >> 7;
  int mBase = (blockIdx.x / nt) << 7;
  int nBase = (blockIdx.x % nt) << 7;

  f4 acc[4][4];
#pragma unroll
  for (int i = 0; i < 4; i++)
#pragma unroll
    for (int j = 0; j < 4; j++) acc[i][j] = (f4)0.f;

  for (int kt = 0; kt < K; kt += 32) {
    __syncthreads();
#pragma unroll
    for (int i = 0; i < 2; i++) {
      int p = i * 256 + tid;   // 0..511
      int r = p >> 2, c = p & 3;
      *(h8*)&As[r][c * 8] = *(const h8*)(A + (size_t)(mBase + r) * K + kt + c * 8);
      *(h8*)&Bs[r][c * 8] = *(const h8*)(B + (size_t)(nBase + r) * K + kt + c * 8);
    }
    __syncthreads();
    h8 af[4], bf[4];
#pragma unroll
    for (int i = 0; i < 4; i++) af[i] = *(const h8*)&As[wr * 64 + i * 16 + l15][g * 8];
#pragma unroll
    for (int j = 0; j < 4; j++) bf[j] = *(const h8*)&Bs[wc * 64 + j * 16 + l15][g * 8];
#pragma unroll
    for (int i = 0; i < 4; i++)
#pragma unroll
      for (int j = 0; j < 4; j++)
        acc[i][j] = __builtin_amdgcn_mfma_f32_16x16x32_f16(bf[j], af[i], acc[i][j], 0, 0, 0);
  }

#pragma unroll
  for (int i = 0; i < 4; i++)
#pragma unroll
    for (int j = 0; j < 4; j++) {
      int row  = mBase + wr * 64 + i * 16 + l15;
      int colb = nBase + wc * 64 + j * 16 + g * 4;
      f4 bv = *(const f4*)(bias + colb);
      f4 v  = acc[i][j] + bv;
      if (OUT_F32) {
        *(f4*)&((float*)Cout)[(size_t)row * N + colb] = v;
      } else {
        h4 o; o[0] = (_Float16)v[0]; o[1] = (_Float16)v[1];
        o[2] = (_Float16)v[2]; o[3] = (_Float16)v[3];
        *(h4*)&((_Float16*)Cout)[(size_t)row * N + colb] = o;
      }
    }
}

// ---------------- RoPE (in-place on qkv f16), folds attn scale into Q ----------------
__global__ __launch_bounds__(256) void k_rope(_Float16* __restrict__ qkv,
                                              const float* __restrict__ cosb,
                                              const float* __restrict__ sinb) {
  int idx = blockIdx.x * 256 + threadIdx.x;  // 4096*16*10
  int s = idx / 160;
  int rem = idx % 160;
  int h = rem / 10;
  int d4 = (rem % 10) * 4;
  const float qscale = 0.11180339887498949f;  // 80^-0.5
  f4 c1 = *(const f4*)(cosb + s * 80 + d4);
  f4 s1 = *(const f4*)(sinb + s * 80 + d4);
  f4 c2 = *(const f4*)(cosb + s * 80 + d4 + 40);
  f4 s2 = *(const f4*)(sinb + s * 80 + d4 + 40);
  // Q part
  {
    _Float16* p = qkv + (size_t)s * QKV_LD + h * HD + d4;
    h4 x1 = *(h4*)p, x2 = *(h4*)(p + 40);
    h4 o1, o2;
#pragma unroll
    for (int j = 0; j < 4; j++) {
      float a = (float)x1[j], b = (float)x2[j];
      o1[j] = (_Float16)((a * c1[j] - b * s1[j]) * qscale);
      o2[j] = (_Float16)((b * c2[j] + a * s2[j]) * qscale);
    }
    *(h4*)p = o1; *(h4*)(p + 40) = o2;
  }
  // K part
  {
    _Float16* p = qkv + (size_t)s * QKV_LD + EMB + h * HD + d4;
    h4 x1 = *(h4*)p, x2 = *(h4*)(p + 40);
    h4 o1, o2;
#pragma unroll
    for (int j = 0; j < 4; j++) {
      float a = (float)x1[j], b = (float)x2[j];
      o1[j] = (_Float16)(a * c1[j] - b * s1[j]);
      o2[j] = (_Float16)(b * c2[j] + a * s2[j]);
    }
    *(h4*)p = o1; *(h4*)(p + 40) = o2;
  }
}

// ---------------- Flash attention ----------------
// Block = (head, 64 q-rows); 4 waves x 16 q-rows each; KV tiles of 64.
// Swapped QK^T: st = mfma(K_frag, Q_frag) = S^T tile (kv rows x 16 q cols).
// Softmax reduce over kv = regs + shfl_xor(16,32). P^T C-frag feeds PV directly
// as B operand; A operand = V^T rows from transposed LDS tile -> O = OUT^T frag.
__global__ __launch_bounds__(256) void k_attn(const _Float16* __restrict__ qkv,
                                              _Float16* __restrict__ out) {
  __shared__ _Float16 Kl[64][84];
  __shared__ _Float16 Vt[80][68];
  int tid = threadIdx.x;
  int lane = tid & 63, wave = tid >> 6;
  int l15 = lane & 15, g = lane >> 4;
  int h = blockIdx.x & 15;
  int qb = blockIdx.x >> 4;

  // Q fragments in registers (B-operand layout): Q[q=l15][d = ks*16 + g*4 + j]
  int qrow = qb * 64 + wave * 16 + l15;
  const _Float16* qp = qkv + (size_t)qrow * QKV_LD + h * HD;
  h4 qf[5];
#pragma unroll
  for (int ks = 0; ks < 5; ks++) qf[ks] = *(const h4*)(qp + ks * 16 + g * 4);

  float m = -1e30f, lsum = 0.f;
  f4 O[5];
#pragma unroll
  for (int d = 0; d < 5; d++) O[d] = (f4)0.f;

  for (int t = 0; t < SEQ / 64; t++) {
    int kvBase = t * 64;
    __syncthreads();
    // stage K tile [64][80] (padded 84)
#pragma unroll
    for (int i = 0; i < 5; i++) {
      int idx = i * 256 + tid;  // 0..1279
      int row = idx / 20, q4 = idx % 20;
      *(h4*)&Kl[row][q4 * 4] =
          *(const h4*)(qkv + (size_t)(kvBase + row) * QKV_LD + EMB + h * HD + q4 * 4);
    }
    // stage V transposed: Vt[d][kv] (padded 68), paired rows -> 4B writes
#pragma unroll
    for (int i = 0; i < 3; i++) {
      int idx = i * 256 + tid;
      if (idx < 640) {
        int rp = idx / 20, q4 = idx % 20;
        const _Float16* v0p = qkv + (size_t)(kvBase + rp * 2) * QKV_LD + 2 * EMB + h * HD + q4 * 4;
        h4 v0 = *(const h4*)v0p;
        h4 v1 = *(const h4*)(v0p + QKV_LD);
#pragma unroll
        for (int j = 0; j < 4; j++) {
          h2 pr; pr[0] = v0[j]; pr[1] = v1[j];
          *(h2*)&Vt[q4 * 4 + j][rp * 2] = pr;
        }
      }
    }
    __syncthreads();

    // QK^T -> S^T tile (64 kv x 16 q), fp32
    f4 st[4];
#pragma unroll
    for (int kvs = 0; kvs < 4; kvs++) st[kvs] = (f4)0.f;
#pragma unroll
    for (int kvs = 0; kvs < 4; kvs++)
#pragma unroll
      for (int ks = 0; ks < 5; ks++) {
        h4 a = *(const h4*)&Kl[kvs * 16 + l15][ks * 16 + g * 4];
        st[kvs] = __builtin_amdgcn_mfma_f32_16x16x16f16(a, qf[ks], st[kvs], 0, 0, 0);
      }

    // online softmax (reduce over kv: 4 regs x 4 subtiles, then lanes ^16, ^32)
    float pm = -1e30f;
#pragma unroll
    for (int kvs = 0; kvs < 4; kvs++)
#pragma unroll
      for (int r = 0; r < 4; r++) pm = fmaxf(pm, st[kvs][r]);
    pm = fmaxf(pm, __shfl_xor(pm, 16));
    pm = fmaxf(pm, __shfl_xor(pm, 32));
    float mn = fmaxf(m, pm);
    float fac = __expf(m - mn);
    float rs = 0.f;
    h4 pb[4];
#pragma unroll
    for (int kvs = 0; kvs < 4; kvs++)
#pragma unroll
      for (int r = 0; r < 4; r++) {
        float p = __expf(st[kvs][r] - mn);
        rs += p;
        pb[kvs][r] = (_Float16)p;
      }
    rs += __shfl_xor(rs, 16);
    rs += __shfl_xor(rs, 32);
    lsum = lsum * fac + rs;
    m = mn;
#pragma unroll
    for (int d = 0; d < 5; d++) O[d] *= fac;

    // PV: O^T[d][q] += V^T[d][kv] * P^T[kv][q]
#pragma unroll
    for (int d5 = 0; d5 < 5; d5++)
#pragma unroll
      for (int kvs = 0; kvs < 4; kvs++) {
        h4 a = *(const h4*)&Vt[d5 * 16 + l15][kvs * 16 + g * 4];
        O[d5] = __builtin_amdgcn_mfma_f32_16x16x16f16(a, pb[kvs], O[d5], 0, 0, 0);
      }
  }

  float inv = 1.0f / lsum;
  _Float16* op = out + (size_t)qrow * EMB + h * HD;  // col q == l15 == same row as qf
#pragma unroll
  for (int d5 = 0; d5 < 5; d5++) {
    h4 o;
#pragma unroll
    for (int r = 0; r < 4; r++) o[r] = (_Float16)(O[d5][r] * inv);
    *(h4*)(op + d5 * 16 + g * 4) = o;
  }
}

extern "C" void kernel_launch(void* const* d_in, const int* in_sizes, int n_in,
                              void* d_out, int out_size, void* d_ws, size_t ws_size,
                              hipStream_t stream) {
  const float* hidden = (const float*)d_in[0];
  const float* cosb   = (const float*)d_in[1];
  const float* sinb   = (const float*)d_in[2];
  const float* Wqkv   = (const float*)d_in[3];
  const float* bqkv   = (const float*)d_in[4];
  const float* Wproj  = (const float*)d_in[5];
  const float* bproj  = (const float*)d_in[6];

  char* ws = (char*)d_ws;
  _Float16* Ah   = (_Float16*)(ws);                              // 4096x1280 (reused as attn_out)
  _Float16* WqT  = (_Float16*)(ws + 10485760);                   // 3840x1280
  _Float16* WpT  = (_Float16*)(ws + 10485760 + 9830400);         // 1280x1280
  _Float16* qkvb = (_Float16*)(ws + 10485760 + 9830400 + 3276800); // 4096x3840
  _Float16* attn = Ah;

  k_convert<<<(SEQ * EMB / 4 + 255) / 256, 256, 0, stream>>>(hidden, Ah, SEQ * EMB / 4);
  k_transpose<<<(EMB / 64) * (3 * EMB / 64), 256, 0, stream>>>(Wqkv, WqT, EMB, 3 * EMB);
  k_transpose<<<(EMB / 64) * (EMB / 64), 256, 0, stream>>>(Wproj, WpT, EMB, EMB);
  k_gemm<false><<<(SEQ / 128) * (3 * EMB / 128), 256, 0, stream>>>(Ah, WqT, bqkv, (void*)qkvb,
                                                                   SEQ, 3 * EMB, EMB);
  k_rope<<<(SEQ * NH * 10) / 256, 256, 0, stream>>>(qkvb, cosb, sinb);
  k_attn<<<NH * (SEQ / 64), 256, 0, stream>>>(qkvb, attn);
  k_gemm<true><<<(SEQ / 128) * (EMB / 128), 256, 0, stream>>>(attn, WpT, bproj, d_out,
                                                              SEQ, EMB, EMB);
}

// Round 7
// 336.308 us; speedup vs baseline: 1.0165x; 1.0165x over previous
//
#include <hip/hip_runtime.h>
#include <hip/hip_bf16.h>
#include <cstdint>
#include <cstddef>

typedef _Float16 h2 __attribute__((ext_vector_type(2)));
typedef _Float16 h4 __attribute__((ext_vector_type(4)));
typedef _Float16 h8 __attribute__((ext_vector_type(8)));
typedef float    f4 __attribute__((ext_vector_type(4)));

#define SEQ 4096
#define EMB 1280
#define NH 16
#define HD 80
#define QKV_LD 3840

// ---------------- fp32 -> f16 convert ----------------
__global__ __launch_bounds__(256) void k_convert(const float* __restrict__ in,
                                                 _Float16* __restrict__ out, int n4) {
  int i = blockIdx.x * 256 + threadIdx.x;
  if (i < n4) {
    f4 v = ((const f4*)in)[i];
    h4 o; o[0] = (_Float16)v[0]; o[1] = (_Float16)v[1];
    o[2] = (_Float16)v[2]; o[3] = (_Float16)v[3];
    ((h4*)out)[i] = o;
  }
}

// ---------------- transpose + convert: in (R,C) fp32 -> out (C,R) f16 ----------------
__global__ __launch_bounds__(256) void k_transpose(const float* __restrict__ in,
                                                   _Float16* __restrict__ out, int R, int C) {
  __shared__ _Float16 tile[64][68];
  int ct = C >> 6;
  int rB = (blockIdx.x / ct) << 6;
  int cB = (blockIdx.x % ct) << 6;
#pragma unroll 4
  for (int i = 0; i < 16; i++) {
    int idx = i * 256 + threadIdx.x;
    int r = idx >> 6, c = idx & 63;
    tile[r][c] = (_Float16)in[(size_t)(rB + r) * C + cB + c];
  }
  __syncthreads();
#pragma unroll 4
  for (int i = 0; i < 16; i++) {
    int idx = i * 256 + threadIdx.x;
    int c = idx >> 6, r = idx & 63;
    out[(size_t)(cB + c) * R + rB + r] = tile[r][c];
  }
}

// ---------------- GEMM (round-1 VERIFIED): C(M,N) = A(M,K) * B(N,K)^T + bias ----------------
template <bool OUT_F32>
__global__ __launch_bounds__(256) void k_gemm(const _Float16* __restrict__ A,
                                              const _Float16* __restrict__ B,
                                              const float* __restrict__ bias,
                                              void* __restrict__ Cout,
                                              int M, int N, int K) {
  __shared__ _Float16 As[128][40];
  __shared__ _Float16 Bs[128][40];
  int tid = threadIdx.x;
  int lane = tid & 63, wave = tid >> 6;
  int wr = wave >> 1, wc = wave & 1;
  int l15 = lane & 15, g = lane >> 4;
  int nt = N >> 7;
  int mBase = (blockIdx.x / nt) << 7;
  int nBase = (blockIdx.x % nt) << 7;

  f4 acc[4][4];
#pragma unroll
  for (int i = 0; i < 4; i++)
#pragma unroll
    for (int j = 0; j < 4; j++) acc[i][j] = (f4)0.f;

  for (int kt = 0; kt < K; kt += 32) {
    __syncthreads();
#pragma unroll
    for (int i = 0; i < 2; i++) {
      int p = i * 256 + tid;   // 0..511
      int r = p >> 2, c = p & 3;
      *(h8*)&As[r][c * 8] = *(const h8*)(A + (size_t)(mBase + r) * K + kt + c * 8);
      *(h8*)&Bs[r][c * 8] = *(const h8*)(B + (size_t)(nBase + r) * K + kt + c * 8);
    }
    __syncthreads();
    h8 af[4], bf[4];
#pragma unroll
    for (int i = 0; i < 4; i++) af[i] = *(const h8*)&As[wr * 64 + i * 16 + l15][g * 8];
#pragma unroll
    for (int j = 0; j < 4; j++) bf[j] = *(const h8*)&Bs[wc * 64 + j * 16 + l15][g * 8];
#pragma unroll
    for (int i = 0; i < 4; i++)
#pragma unroll
      for (int j = 0; j < 4; j++)
        acc[i][j] = __builtin_amdgcn_mfma_f32_16x16x32_f16(bf[j], af[i], acc[i][j], 0, 0, 0);
  }

#pragma unroll
  for (int i = 0; i < 4; i++)
#pragma unroll
    for (int j = 0; j < 4; j++) {
      int row  = mBase + wr * 64 + i * 16 + l15;
      int colb = nBase + wc * 64 + j * 16 + g * 4;
      f4 bv = *(const f4*)(bias + colb);
      f4 v  = acc[i][j] + bv;
      if (OUT_F32) {
        *(f4*)&((float*)Cout)[(size_t)row * N + colb] = v;
      } else {
        h4 o; o[0] = (_Float16)v[0]; o[1] = (_Float16)v[1];
        o[2] = (_Float16)v[2]; o[3] = (_Float16)v[3];
        *(h4*)&((_Float16*)Cout)[(size_t)row * N + colb] = o;
      }
    }
}

// ---------------- RoPE (round-1 exact): in-place f16, Q scaled by 80^-0.5 ----------------
__global__ __launch_bounds__(256) void k_rope(_Float16* __restrict__ qkv,
                                              const float* __restrict__ cosb,
                                              const float* __restrict__ sinb) {
  int idx = blockIdx.x * 256 + threadIdx.x;  // 4096*16*10
  int s = idx / 160;
  int rem = idx % 160;
  int h = rem / 10;
  int d4 = (rem % 10) * 4;
  const float qscale = 0.11180339887498949f;  // 80^-0.5
  f4 c1 = *(const f4*)(cosb + s * 80 + d4);
  f4 s1 = *(const f4*)(sinb + s * 80 + d4);
  f4 c2 = *(const f4*)(cosb + s * 80 + d4 + 40);
  f4 s2 = *(const f4*)(sinb + s * 80 + d4 + 40);
  {
    _Float16* p = qkv + (size_t)s * QKV_LD + h * HD + d4;
    h4 x1 = *(h4*)p, x2 = *(h4*)(p + 40);
    h4 o1, o2;
#pragma unroll
    for (int j = 0; j < 4; j++) {
      float a = (float)x1[j], b = (float)x2[j];
      o1[j] = (_Float16)((a * c1[j] - b * s1[j]) * qscale);
      o2[j] = (_Float16)((b * c2[j] + a * s2[j]) * qscale);
    }
    *(h4*)p = o1; *(h4*)(p + 40) = o2;
  }
  {
    _Float16* p = qkv + (size_t)s * QKV_LD + EMB + h * HD + d4;
    h4 x1 = *(h4*)p, x2 = *(h4*)(p + 40);
    h4 o1, o2;
#pragma unroll
    for (int j = 0; j < 4; j++) {
      float a = (float)x1[j], b = (float)x2[j];
      o1[j] = (_Float16)(a * c1[j] - b * s1[j]);
      o2[j] = (_Float16)(b * c2[j] + a * s2[j]);
    }
    *(h4*)p = o1; *(h4*)(p + 40) = o2;
  }
}

// ---------------- V global transpose: VT[(h*80+d)*SEQ + s] = V[s][h*80+d] ----------------
__global__ __launch_bounds__(256) void k_vt(const _Float16* __restrict__ qkv,
                                            _Float16* __restrict__ vt) {
  __shared__ __align__(16) _Float16 T[64][88];  // 176B rows: h8 writes 16B-aligned
  int tid = threadIdx.x;
  int h = blockIdx.x & 15;
  int sb = (blockIdx.x >> 4) << 6;
  const _Float16* src = qkv + 2 * EMB + h * HD;
#pragma unroll
  for (int i = 0; i < 3; ++i) {
    int u = i * 256 + tid;  // 640 h8 units: row=u/10, c8=u%10
    if (u < 640) {
      int row = u / 10, c8 = u % 10;
      *(h8*)&T[row][c8 * 8] = *(const h8*)(src + (size_t)(sb + row) * QKV_LD + c8 * 8);
    }
  }
  __syncthreads();
#pragma unroll
  for (int i = 0; i < 5; ++i) {
    int u = i * 256 + tid;  // 1280 h4 units: d=u>>4, s4=u&15
    int d = u >> 4, s4 = u & 15;
    h4 o;
#pragma unroll
    for (int j = 0; j < 4; ++j) o[j] = T[s4 * 4 + j][d];
    *(h4*)(vt + (size_t)(h * HD + d) * SEQ + sb + s4 * 4) = o;
  }
}

// ---------------- Flash attention: ROUND-1 EXACT except (a) staging addresses
// hoisted out of the t-loop, (b) V staged from pre-transposed VT with aligned
// h4 row-writes into the SAME Vt[80][68] layout (reads untouched).
__global__ __launch_bounds__(256) void k_attn(const _Float16* __restrict__ qkv,
                                              const _Float16* __restrict__ vt,
                                              _Float16* __restrict__ out) {
  __shared__ _Float16 Kl[64][84];
  __shared__ _Float16 Vt[80][68];
  int tid = threadIdx.x;
  int lane = tid & 63, wave = tid >> 6;
  int l15 = lane & 15, g = lane >> 4;
  int h = blockIdx.x & 15;
  int qb = blockIdx.x >> 4;

  // Q fragments (B-operand layout): Q[q=l15][d = ks*16 + g*4 + j]
  int qrow = qb * 64 + wave * 16 + l15;
  const _Float16* qp = qkv + (size_t)qrow * QKV_LD + h * HD;
  h4 qf[5];
#pragma unroll
  for (int ks = 0; ks < 5; ks++) qf[ks] = *(const h4*)(qp + ks * 16 + g * 4);

  // Hoisted K staging pointers: 1280 h4-units, u = i*256+tid: row=u/20, q4=u%20
  const _Float16* gk[5];
  _Float16* lk[5];
#pragma unroll
  for (int i = 0; i < 5; i++) {
    int u = i * 256 + tid;
    gk[i] = qkv + EMB + h * HD + (size_t)(u / 20) * QKV_LD + (u % 20) * 4;
    lk[i] = &Kl[u / 20][(u % 20) * 4];
  }
  // Hoisted V staging pointers: 640 h8-units from VT: u = {tid, 256+tid, 512+(tid&127)}
  //   d = u>>3 (0..79), kv8 = u&7
  int u0 = tid, u1 = 256 + tid, u2 = 512 + (tid & 127);
  const _Float16* gv0 = vt + (size_t)(h * HD + (u0 >> 3)) * SEQ + (u0 & 7) * 8;
  const _Float16* gv1 = vt + (size_t)(h * HD + (u1 >> 3)) * SEQ + (u1 & 7) * 8;
  const _Float16* gv2 = vt + (size_t)(h * HD + (u2 >> 3)) * SEQ + (u2 & 7) * 8;
  _Float16* lv0 = &Vt[u0 >> 3][(u0 & 7) * 8];
  _Float16* lv1 = &Vt[u1 >> 3][(u1 & 7) * 8];
  _Float16* lv2 = &Vt[u2 >> 3][(u2 & 7) * 8];

  float m = -1e30f, lsum = 0.f;
  f4 O[5];
#pragma unroll
  for (int d = 0; d < 5; d++) O[d] = (f4)0.f;

  for (int t = 0; t < 64; t++) {
    __syncthreads();
    // stage K tile (linear, same [64][84] layout as round 1)
    size_t ka = (size_t)t * (size_t)(64 * QKV_LD);
    int va = t * 64;
#pragma unroll
    for (int i = 0; i < 5; i++) *(h4*)lk[i] = *(const h4*)(gk[i] + ka);
    // stage V tile rows from VT (aligned h4 pairs into Vt[80][68])
    {
      h8 v0 = *(const h8*)(gv0 + va);
      h8 v1 = *(const h8*)(gv1 + va);
      h4 a, b;
      a[0] = v0[0]; a[1] = v0[1]; a[2] = v0[2]; a[3] = v0[3];
      b[0] = v0[4]; b[1] = v0[5]; b[2] = v0[6]; b[3] = v0[7];
      *(h4*)lv0 = a; *(h4*)(lv0 + 4) = b;
      a[0] = v1[0]; a[1] = v1[1]; a[2] = v1[2]; a[3] = v1[3];
      b[0] = v1[4]; b[1] = v1[5]; b[2] = v1[6]; b[3] = v1[7];
      *(h4*)lv1 = a; *(h4*)(lv1 + 4) = b;
      if (tid < 128) {
        h8 v2 = *(const h8*)(gv2 + va);
        a[0] = v2[0]; a[1] = v2[1]; a[2] = v2[2]; a[3] = v2[3];
        b[0] = v2[4]; b[1] = v2[5]; b[2] = v2[6]; b[3] = v2[7];
        *(h4*)lv2 = a; *(h4*)(lv2 + 4) = b;
      }
    }
    __syncthreads();

    // QK^T -> S^T tile (64 kv x 16 q), fp32  (round-1 exact)
    f4 st[4];
#pragma unroll
    for (int kvs = 0; kvs < 4; kvs++) st[kvs] = (f4)0.f;
#pragma unroll
    for (int kvs = 0; kvs < 4; kvs++)
#pragma unroll
      for (int ks = 0; ks < 5; ks++) {
        h4 a = *(const h4*)&Kl[kvs * 16 + l15][ks * 16 + g * 4];
        st[kvs] = __builtin_amdgcn_mfma_f32_16x16x16f16(a, qf[ks], st[kvs], 0, 0, 0);
      }

    // online softmax (round-1 exact)
    float pm = -1e30f;
#pragma unroll
    for (int kvs = 0; kvs < 4; kvs++)
#pragma unroll
      for (int r = 0; r < 4; r++) pm = fmaxf(pm, st[kvs][r]);
    pm = fmaxf(pm, __shfl_xor(pm, 16));
    pm = fmaxf(pm, __shfl_xor(pm, 32));
    float mn = fmaxf(m, pm);
    float fac = __expf(m - mn);
    float rs = 0.f;
    h4 pb[4];
#pragma unroll
    for (int kvs = 0; kvs < 4; kvs++)
#pragma unroll
      for (int r = 0; r < 4; r++) {
        float p = __expf(st[kvs][r] - mn);
        rs += p;
        pb[kvs][r] = (_Float16)p;
      }
    rs += __shfl_xor(rs, 16);
    rs += __shfl_xor(rs, 32);
    lsum = lsum * fac + rs;
    m = mn;
#pragma unroll
    for (int d = 0; d < 5; d++) O[d] *= fac;

    // PV (round-1 exact): O^T[d][q] += V^T[d][kv] * P^T[kv][q]
#pragma unroll
    for (int d5 = 0; d5 < 5; d5++)
#pragma unroll
      for (int kvs = 0; kvs < 4; kvs++) {
        h4 a = *(const h4*)&Vt[d5 * 16 + l15][kvs * 16 + g * 4];
        O[d5] = __builtin_amdgcn_mfma_f32_16x16x16f16(a, pb[kvs], O[d5], 0, 0, 0);
      }
  }

  float inv = 1.0f / lsum;
  _Float16* op = out + (size_t)qrow * EMB + h * HD;
#pragma unroll
  for (int d5 = 0; d5 < 5; d5++) {
    h4 o;
#pragma unroll
    for (int r = 0; r < 4; r++) o[r] = (_Float16)(O[d5][r] * inv);
    *(h4*)(op + d5 * 16 + g * 4) = o;
  }
}

extern "C" void kernel_launch(void* const* d_in, const int* in_sizes, int n_in,
                              void* d_out, int out_size, void* d_ws, size_t ws_size,
                              hipStream_t stream) {
  const float* hidden = (const float*)d_in[0];
  const float* cosb   = (const float*)d_in[1];
  const float* sinb   = (const float*)d_in[2];
  const float* Wqkv   = (const float*)d_in[3];
  const float* bqkv   = (const float*)d_in[4];
  const float* Wproj  = (const float*)d_in[5];
  const float* bproj  = (const float*)d_in[6];

  // ws layout — max footprint 55,050,240 B (== round-1's PROVEN bound):
  //   Ah   @ 0        : 10485760  hidden f16, later attention output
  //   WqT  @ 10485760 :  9830400  dead after QKV GEMM
  //   VT   @ 10485760 : 10485760  written by k_vt AFTER the GEMM (over WqT)
  //   WpT  @ 20316160 :  3276800  written AFTER attention (over VT tail; VT dead)
  //   qkvb @ 23592960 : 31457280  (same as round 1)
  char* ws = (char*)d_ws;
  _Float16* Ah   = (_Float16*)(ws);
  _Float16* WqT  = (_Float16*)(ws + 10485760);
  _Float16* VT   = (_Float16*)(ws + 10485760);
  _Float16* WpT  = (_Float16*)(ws + 20316160);
  _Float16* qkvb = (_Float16*)(ws + 23592960);

  k_convert<<<SEQ * EMB / 4 / 256, 256, 0, stream>>>(hidden, Ah, SEQ * EMB / 4);
  k_transpose<<<(EMB / 64) * (3 * EMB / 64), 256, 0, stream>>>(Wqkv, WqT, EMB, 3 * EMB);
  k_gemm<false><<<(SEQ / 128) * (3 * EMB / 128), 256, 0, stream>>>(
      Ah, WqT, bqkv, (void*)qkvb, SEQ, 3 * EMB, EMB);
  k_rope<<<(SEQ * NH * 10) / 256, 256, 0, stream>>>(qkvb, cosb, sinb);
  k_vt<<<NH * (SEQ / 64), 256, 0, stream>>>(qkvb, VT);            // VT over dead WqT
  k_attn<<<NH * (SEQ / 64), 256, 0, stream>>>(qkvb, VT, Ah);      // Ah's hidden is dead
  k_transpose<<<(EMB / 64) * (EMB / 64), 256, 0, stream>>>(Wproj, WpT, EMB, EMB);
  k_gemm<true><<<(SEQ / 128) * (EMB / 128), 256, 0, stream>>>(
      Ah, WpT, bproj, d_out, SEQ, EMB, EMB);
}